// Round 15
// baseline (105.677 us; speedup 1.0000x reference)
//
#include <hip/hip_runtime.h>

// GCNConv forward via radix-partitioned CSR build + bf16 register gather.
// t[i] = bf16( dis[i]*(x@W)[i] );  out[c] = b + dis[c]*( t[c] + sum_{edges r->c} t[r] )
//
// NOTE: workspace layout keeps t 256-B aligned — a 32-B-aligned t makes every
// gathered 128-B row straddle two cache lines (R10: FETCH +78%, +9 us).
// CSR build uses deterministic per-(block,bucket) offsets (radix-sort partition):
// no global reservation atomics (R9 lesson: per-address chains serialize NBLK-deep).
// bf16 unpack uses the low-bits-as-noise trick: as_float(u) for the odd element
// (noise < 2^-7 relative, same order as bf16 rounding) — saves 4 ANDs per uint4.

#define D 64
#define BSH 8            // bucket shift: 256 cols per bucket
#define BCOLS 256
#define MAXNB 512        // supports n <= 131072 (row fits in 20 bits)
#define BM 128           // GEMM rows per block
#define NBLK3 512        // partition blocks
#define BT3 512          // partition threads per block
#define BB_CACHE 6144    // bucket_build LDS edge cache (24 KB)

__device__ inline unsigned short f2bf(float f) {   // RNE fp32 -> bf16
    unsigned u = __float_as_uint(f);
    return (unsigned short)((u + 0x7FFFu + ((u >> 16) & 1u)) >> 16);
}

// ---------- fast path: radix-partitioned CSR build ----------

// Pass 1: per-block bucket histogram of its chunk -> hist[block][MAXNB].
__global__ __launch_bounds__(BT3) void bhist_kernel(const int* __restrict__ col, int* __restrict__ hist,
                                                    int e, int chunk) {
    __shared__ int h[MAXNB];
    int tid = threadIdx.x;
    for (int i = tid; i < MAXNB; i += BT3) h[i] = 0;
    __syncthreads();
    int i0 = blockIdx.x * chunk;
    int i1 = i0 + chunk; if (i1 > e) i1 = e;
    if (((e | chunk) & 3) == 0) {
        for (int i = i0 + tid * 4; i < i1; i += BT3 * 4) {
            int4 c4 = *(const int4*)(col + i);
            atomicAdd(&h[c4.x >> BSH], 1);
            atomicAdd(&h[c4.y >> BSH], 1);
            atomicAdd(&h[c4.z >> BSH], 1);
            atomicAdd(&h[c4.w >> BSH], 1);
        }
    } else {
        for (int i = i0 + tid; i < i1; i += BT3)
            atomicAdd(&h[col[i] >> BSH], 1);
    }
    __syncthreads();
    for (int i = tid; i < MAXNB; i += BT3)
        hist[blockIdx.x * MAXNB + i] = h[i];
}

// Pass 2: one block per bucket: exclusive scan of hist[:, b] across NBLK3 rows (in place),
// bucket total -> total[b].
__global__ __launch_bounds__(256) void colscan_kernel(int* __restrict__ hist, int* __restrict__ total) {
    __shared__ int s[256];
    int b = blockIdx.x;
    int tid = threadIdx.x;
    int v0 = hist[(2 * tid) * MAXNB + b];
    int v1 = hist[(2 * tid + 1) * MAXNB + b];
    int sum = v0 + v1;
    s[tid] = sum;
    __syncthreads();
#pragma unroll
    for (int d = 1; d < 256; d <<= 1) {
        int add = (tid >= d) ? s[tid - d] : 0;
        __syncthreads();
        s[tid] += add;
        __syncthreads();
    }
    int ex = s[tid] - sum;
    hist[(2 * tid) * MAXNB + b] = ex;
    hist[(2 * tid + 1) * MAXNB + b] = ex + v0;
    if (tid == 255) total[b] = s[255];
}

// Pass 3: exclusive scan of total[0..MAXNB) -> base (base[nb] = e via zero padding).
__global__ __launch_bounds__(MAXNB) void basescan_kernel(const int* __restrict__ total, int* __restrict__ base,
                                                         int nb, int e) {
    __shared__ int s[MAXNB];
    int tid = threadIdx.x;
    int v = total[tid];
    s[tid] = v;
    __syncthreads();
#pragma unroll
    for (int d = 1; d < MAXNB; d <<= 1) {
        int add = (tid >= d) ? s[tid - d] : 0;
        __syncthreads();
        s[tid] += add;
        __syncthreads();
    }
    base[tid] = s[tid] - v;
    if (tid == 0) base[nb] = e;
}

// Pass 4: scatter edges bucket-grouped. Deterministic start = base[b] + hist[block][b];
// LDS-only cursors, no global atomics. binned[pos] = ((col&255) << 20) | row.
__global__ __launch_bounds__(BT3) void bscatter_kernel(const int* __restrict__ row, const int* __restrict__ col,
                                                       const int* __restrict__ hist, const int* __restrict__ base,
                                                       unsigned int* __restrict__ binned, int e, int chunk) {
    __shared__ int h[MAXNB];
    int tid = threadIdx.x;
    for (int i = tid; i < MAXNB; i += BT3)
        h[i] = base[i] + hist[blockIdx.x * MAXNB + i];
    __syncthreads();
    int i0 = blockIdx.x * chunk;
    int i1 = i0 + chunk; if (i1 > e) i1 = e;
    if (((e | chunk) & 3) == 0) {
        for (int i = i0 + tid * 4; i < i1; i += BT3 * 4) {
            int4 c4 = *(const int4*)(col + i);
            int4 r4 = *(const int4*)(row + i);
            int bk, pos;
            bk = c4.x >> BSH; pos = atomicAdd(&h[bk], 1);
            binned[pos] = ((unsigned int)(c4.x & (BCOLS - 1)) << 20) | (unsigned int)r4.x;
            bk = c4.y >> BSH; pos = atomicAdd(&h[bk], 1);
            binned[pos] = ((unsigned int)(c4.y & (BCOLS - 1)) << 20) | (unsigned int)r4.y;
            bk = c4.z >> BSH; pos = atomicAdd(&h[bk], 1);
            binned[pos] = ((unsigned int)(c4.z & (BCOLS - 1)) << 20) | (unsigned int)r4.z;
            bk = c4.w >> BSH; pos = atomicAdd(&h[bk], 1);
            binned[pos] = ((unsigned int)(c4.w & (BCOLS - 1)) << 20) | (unsigned int)r4.w;
        }
    } else {
        for (int i = i0 + tid; i < i1; i += BT3) {
            int cl = col[i];
            int bk = cl >> BSH;
            int pos = atomicAdd(&h[bk], 1);
            binned[pos] = ((unsigned int)(cl & (BCOLS - 1)) << 20) | (unsigned int)row[i];
        }
    }
}

// One block (512 threads) per 256-col bucket: per-col hist -> 256-wide scan ->
// offend (int2 per col) + dis + srcs. Binned chunk cached in LDS when it fits.
__global__ __launch_bounds__(512) void bucket_build_kernel(const int* __restrict__ base,
                                                           const unsigned int* __restrict__ binned,
                                                           int* __restrict__ offend,
                                                           float* __restrict__ dis, int* __restrict__ srcs,
                                                           int n) {
    __shared__ int hc[BCOLS];
    __shared__ int ho[BCOLS];
    __shared__ int hcur[BCOLS];
    __shared__ unsigned int bc[BB_CACHE];
    int tid = threadIdx.x;
    int b = blockIdx.x;
    int s0 = base[b], s1 = base[b + 1];
    int m = s1 - s0;
    bool cached = (m <= BB_CACHE);
    if (cached)
        for (int i = tid; i < m; i += 512) bc[i] = binned[s0 + i];
    if (tid < BCOLS) hc[tid] = 0;
    __syncthreads();
    if (cached) {
        for (int i = tid; i < m; i += 512)
            atomicAdd(&hc[(bc[i] >> 20) & (BCOLS - 1)], 1);
    } else {
        for (int i = s0 + tid; i < s1; i += 512)
            atomicAdd(&hc[(binned[i] >> 20) & (BCOLS - 1)], 1);
    }
    __syncthreads();
    int v = 0;
    if (tid < BCOLS) { v = hc[tid]; ho[tid] = v; }
    __syncthreads();
#pragma unroll
    for (int d = 1; d < BCOLS; d <<= 1) {
        int add = (tid < BCOLS && tid >= d) ? ho[tid - d] : 0;
        __syncthreads();
        if (tid < BCOLS) ho[tid] += add;
        __syncthreads();
    }
    if (tid < BCOLS) {
        int col = (b << BSH) + tid;
        if (col < n) {
            int ex = ho[tid] - v;
            ((int2*)offend)[col] = make_int2(s0 + ex, s0 + ho[tid]);
            dis[col] = rsqrtf((float)(v + 1));  // +1 self loop
            hcur[tid] = s0 + ex;
        }
    }
    __syncthreads();
    if (cached) {
        for (int i = tid; i < m; i += 512) {
            unsigned int w = bc[i];
            int lc = (w >> 20) & (BCOLS - 1);
            int pos = atomicAdd(&hcur[lc], 1);
            srcs[pos] = (int)(w & 0xFFFFFu);
        }
    } else {
        for (int i = s0 + tid; i < s1; i += 512) {
            unsigned int w = binned[i];
            int lc = (w >> 20) & (BCOLS - 1);
            int pos = atomicAdd(&hcur[lc], 1);
            srcs[pos] = (int)(w & 0xFFFFFu);
        }
    }
}

// ---------- t = bf16( dis * (x @ W) ): register-tiled fp32 GEMM ----------

__global__ __launch_bounds__(256) void xw_t_gemm_kernel(const float* __restrict__ x, const float* __restrict__ W,
                                                        const float* __restrict__ dis,
                                                        unsigned short* __restrict__ t, int n) {
    __shared__ float xT[D][BM];   // [k][row], 32 KB
    __shared__ float Wl[D][D];    // [k][col], 16 KB
    int tid = threadIdx.x;
    int r0 = blockIdx.x * BM;

    {
        const float4* Wv = (const float4*)W;
        float4* Wd = (float4*)&Wl[0][0];
#pragma unroll
        for (int j = 0; j < 4; ++j) Wd[j * 256 + tid] = Wv[j * 256 + tid];
    }
    {
        int row = tid >> 1;
        int c0 = (tid & 1) * 32;
        int gr = r0 + row;
        if (gr < n) {
            const float4* xv = (const float4*)(x + (size_t)gr * D + c0);
#pragma unroll
            for (int j = 0; j < 8; ++j) {
                float4 v = xv[j];
                int c = c0 + j * 4;
                xT[c + 0][row] = v.x;
                xT[c + 1][row] = v.y;
                xT[c + 2][row] = v.z;
                xT[c + 3][row] = v.w;
            }
        }
    }
    __syncthreads();

    int cg = tid & 15;
    int rg = tid >> 4;
    float acc[8][4];
#pragma unroll
    for (int i = 0; i < 8; ++i)
#pragma unroll
        for (int j = 0; j < 4; ++j) acc[i][j] = 0.0f;

#pragma unroll 8
    for (int k = 0; k < D; ++k) {
        float4 xa = *(const float4*)&xT[k][rg * 8];
        float4 xb = *(const float4*)&xT[k][rg * 8 + 4];
        float4 wv = *(const float4*)&Wl[k][cg * 4];
        float xr[8] = {xa.x, xa.y, xa.z, xa.w, xb.x, xb.y, xb.z, xb.w};
        float wr[4] = {wv.x, wv.y, wv.z, wv.w};
#pragma unroll
        for (int i = 0; i < 8; ++i)
#pragma unroll
            for (int j = 0; j < 4; ++j) acc[i][j] += xr[i] * wr[j];
    }

#pragma unroll
    for (int i = 0; i < 8; ++i) {
        int gr = r0 + rg * 8 + i;
        if (gr < n) {
            float dsc = dis[gr];
            ushort4 o;
            o.x = f2bf(acc[i][0] * dsc); o.y = f2bf(acc[i][1] * dsc);
            o.z = f2bf(acc[i][2] * dsc); o.w = f2bf(acc[i][3] * dsc);
            *(ushort4*)(t + (size_t)gr * D + cg * 4) = o;
        }
    }
}

// ---------- gather: one wave per node, 8-edge subgroups, bf16 rows ----------
// Odd elements use as_float(u) directly (low-bits noise < 2^-7 rel, ~ bf16 rounding).

__device__ inline void add8(float* acc, uint4 u) {
    acc[0] += __uint_as_float(u.x << 16);
    acc[1] += __uint_as_float(u.x);
    acc[2] += __uint_as_float(u.y << 16);
    acc[3] += __uint_as_float(u.y);
    acc[4] += __uint_as_float(u.z << 16);
    acc[5] += __uint_as_float(u.z);
    acc[6] += __uint_as_float(u.w << 16);
    acc[7] += __uint_as_float(u.w);
}

__global__ __launch_bounds__(256) void gather8_kernel(const int* __restrict__ offend,
                                                      const int* __restrict__ srcs,
                                                      const unsigned short* __restrict__ t,
                                                      const float* __restrict__ dis, const float* __restrict__ b,
                                                      float* __restrict__ out, int n) {
    int c    = blockIdx.x * 4 + (threadIdx.x >> 6);
    int lane = threadIdx.x & 63;
    if (c >= n) return;
    int e8 = lane >> 3;   // edge subgroup 0..7
    int d8 = lane & 7;    // 16B chunk of row
    int2 oe = ((const int2*)offend)[c];
    int j0 = oe.x;
    int jend = oe.y;

    float acc[8];
#pragma unroll
    for (int q = 0; q < 8; ++q) acc[q] = 0.0f;

    if (e8 == 0) {  // self-loop term
        uint4 u = *(const uint4*)(t + (size_t)c * D + d8 * 8);
        add8(acc, u);
    }

    for (int jb = j0; jb < jend; jb += 64) {
        int m = jend - jb; if (m > 64) m = 64;
        int sv = (jb + lane < jend) ? srcs[jb + lane] : 0;
        int k = 0;
        for (; k + 32 <= m; k += 32) {   // 4 independent loads in flight
            int r0 = __shfl(sv, k + e8);
            int r1 = __shfl(sv, k + 8 + e8);
            int r2 = __shfl(sv, k + 16 + e8);
            int r3 = __shfl(sv, k + 24 + e8);
            uint4 u0 = *(const uint4*)(t + (size_t)r0 * D + d8 * 8);
            uint4 u1 = *(const uint4*)(t + (size_t)r1 * D + d8 * 8);
            uint4 u2 = *(const uint4*)(t + (size_t)r2 * D + d8 * 8);
            uint4 u3 = *(const uint4*)(t + (size_t)r3 * D + d8 * 8);
            add8(acc, u0); add8(acc, u1); add8(acc, u2); add8(acc, u3);
        }
        for (; k + 16 <= m; k += 16) {
            int r0 = __shfl(sv, k + e8);
            int r1 = __shfl(sv, k + 8 + e8);
            uint4 u0 = *(const uint4*)(t + (size_t)r0 * D + d8 * 8);
            uint4 u1 = *(const uint4*)(t + (size_t)r1 * D + d8 * 8);
            add8(acc, u0); add8(acc, u1);
        }
        for (; k < m; k += 8) {
            int idx = k + e8;
            int r = __shfl(sv, idx);
            if (idx < m) {
                uint4 u = *(const uint4*)(t + (size_t)r * D + d8 * 8);
                add8(acc, u);
            }
        }
    }

#pragma unroll
    for (int s = 8; s < 64; s <<= 1)
#pragma unroll
        for (int q = 0; q < 8; ++q) acc[q] += __shfl_xor(acc[q], s);

    if (e8 == 0) {
        float dsc = dis[c];
        float* op = out + (size_t)c * D + d8 * 8;
        const float* bp = b + d8 * 8;
        float4 o0, o1;
        o0.x = bp[0] + dsc * acc[0]; o0.y = bp[1] + dsc * acc[1];
        o0.z = bp[2] + dsc * acc[2]; o0.w = bp[3] + dsc * acc[3];
        o1.x = bp[4] + dsc * acc[4]; o1.y = bp[5] + dsc * acc[5];
        o1.z = bp[6] + dsc * acc[6]; o1.w = bp[7] + dsc * acc[7];
        *(float4*)op = o0;
        *(float4*)(op + 4) = o1;
    }
}

// ---------- mid fallback: flat hist/scan/fill CSR + gather8 (offend layout) ----------

__global__ __launch_bounds__(256) void cnt_init_kernel(int* __restrict__ cnt, int n) {
    int i = blockIdx.x * 256 + threadIdx.x;
    if (i < n) cnt[i] = 0;
}
__global__ __launch_bounds__(256) void hist_kernel(const int* __restrict__ col, int* __restrict__ cnt, int e) {
    int i = blockIdx.x * 256 + threadIdx.x;
    if (i < e) atomicAdd(&cnt[col[i]], 1);
}
__global__ __launch_bounds__(1024) void scan1_kernel(const int* __restrict__ cnt, float* __restrict__ dis,
                                                     int* __restrict__ offend, int* __restrict__ bsum, int n) {
    __shared__ int s[1024];
    int tid = threadIdx.x;
    int i = blockIdx.x * 1024 + tid;
    int v = (i < n) ? cnt[i] : 0;
    if (i < n) dis[i] = rsqrtf((float)(v + 1));
    s[tid] = v;
    __syncthreads();
#pragma unroll
    for (int d = 1; d < 1024; d <<= 1) {
        int add = (tid >= d) ? s[tid - d] : 0;
        __syncthreads();
        s[tid] += add;
        __syncthreads();
    }
    int incl = s[tid];
    if (i < n) offend[2 * i] = incl - v;
    if (tid == 1023) bsum[blockIdx.x] = incl;
}
__global__ __launch_bounds__(1024) void scan2_kernel(int* __restrict__ bsum, int nb) {
    __shared__ int s[1024];
    int tid = threadIdx.x;
    int v = (tid < nb) ? bsum[tid] : 0;
    s[tid] = v;
    __syncthreads();
#pragma unroll
    for (int d = 1; d < 1024; d <<= 1) {
        int add = (tid >= d) ? s[tid - d] : 0;
        __syncthreads();
        s[tid] += add;
        __syncthreads();
    }
    if (tid < nb) bsum[tid] = s[tid] - v;
}
__global__ __launch_bounds__(1024) void scan3_kernel(int* __restrict__ offend, const int* __restrict__ bsum, int n) {
    int i = blockIdx.x * 1024 + threadIdx.x;
    if (i < n) {
        int o = offend[2 * i] + bsum[blockIdx.x];
        offend[2 * i] = o;
        offend[2 * i + 1] = o;
    }
}
__global__ __launch_bounds__(256) void fill_kernel(const int* __restrict__ row, const int* __restrict__ col,
                                                   int* __restrict__ offend, int* __restrict__ srcs, int e) {
    int i = blockIdx.x * 256 + threadIdx.x;
    if (i < e) {
        int pos = atomicAdd(&offend[2 * col[i] + 1], 1);
        srcs[pos] = row[i];
    }
}

// ---------- last fallback: atomic scatter ----------

__global__ __launch_bounds__(256) void deg_init_kernel(float* __restrict__ deg, int n) {
    int i = blockIdx.x * 256 + threadIdx.x;
    if (i < n) deg[i] = 1.0f;
}
__global__ __launch_bounds__(256) void deg_count_kernel(const int* __restrict__ col, float* __restrict__ deg, int e) {
    int i = blockIdx.x * 256 + threadIdx.x;
    if (i < e) atomicAdd(&deg[col[i]], 1.0f);
}
__global__ __launch_bounds__(256) void deg_rsqrt_kernel(float* __restrict__ deg, int n) {
    int i = blockIdx.x * 256 + threadIdx.x;
    if (i < n) deg[i] = rsqrtf(deg[i]);
}
__global__ __launch_bounds__(256) void xw_kernel(const float* __restrict__ x, const float* __restrict__ W,
                                                 float* __restrict__ xw, int n) {
    __shared__ float Wl[D * D];
    int tid = threadIdx.x;
    for (int i = tid; i < D * D; i += 256) Wl[i] = W[i];
    __syncthreads();
    int lane = tid & 63;
    int row  = blockIdx.x * 4 + (tid >> 6);
    if (row >= n) return;
    float xv = x[(size_t)row * D + lane];
    float acc = 0.0f;
#pragma unroll
    for (int k = 0; k < D; ++k) acc += __shfl(xv, k) * Wl[k * D + lane];
    xw[(size_t)row * D + lane] = acc;
}
__global__ __launch_bounds__(256) void out_init_kernel(const float* __restrict__ xw, const float* __restrict__ dis,
                                                       const float* __restrict__ b, float* __restrict__ out, int n) {
    int i = blockIdx.x * 256 + threadIdx.x;
    if (i < n * D) {
        int node = i >> 6;
        float d = dis[node];
        out[i] = b[i & 63] + d * d * xw[i];
    }
}
__global__ __launch_bounds__(256) void scatter_kernel(const int* __restrict__ row, const int* __restrict__ col,
                                                      const float* __restrict__ dis, const float* __restrict__ xw,
                                                      float* __restrict__ out, int e) {
    int idx  = blockIdx.x * 4 + (threadIdx.x >> 6);
    int lane = threadIdx.x & 63;
    if (idx >= e) return;
    int r = row[idx], c = col[idx];
    float w = dis[r] * dis[c];
    atomicAdd(&out[(size_t)c * D + lane], w * xw[(size_t)r * D + lane]);
}

// ---------- launch ----------

extern "C" void kernel_launch(void* const* d_in, const int* in_sizes, int n_in,
                              void* d_out, int out_size, void* d_ws, size_t ws_size,
                              hipStream_t stream) {
    const float* x  = (const float*)d_in[0];
    const int*   ei = (const int*)d_in[1];
    const float* W  = (const float*)d_in[2];
    const float* b  = (const float*)d_in[3];
    float*       out = (float*)d_out;

    int n = in_sizes[0] / D;   // 100000
    int e = in_sizes[1] / 2;   // 1600000
    const int* row = ei;
    const int* col = ei + e;

    size_t nA = ((size_t)n + 255) & ~(size_t)255;  // multiple of 256 elems -> 1 KB
    int nb = (n + BCOLS - 1) >> BSH;

    // fast: hist[NBLK3*MAXNB] | total[512] base[520] pad (2048 ints) | offend[2*nA] | dis[nA] |
    //       t[nA*D] bf16 | binned[e] srcs[e].  All section sizes 256-B multiples -> t 256-B aligned.
    size_t histN = (size_t)NBLK3 * MAXNB;
    size_t fast_needed = (histN + 2048) * 4 + 2 * nA * 4 + nA * 4 + nA * D * 2 + 2 * (size_t)e * 4;
    size_t mid_needed  = (2 * nA + nA + 1024) * 4 + nA * 4 + nA * D * 2 + (size_t)e * 4;

    if (n <= 131072 && nb <= MAXNB && ws_size >= fast_needed) {
        int*   hist   = (int*)d_ws;
        int*   total  = hist + histN;
        int*   base   = total + 512;
        int*   offend = hist + histN + 2048;
        float* dis    = (float*)(offend + 2 * nA);
        unsigned short* t = (unsigned short*)(dis + nA);
        unsigned int* binned = (unsigned int*)(t + nA * D);
        int*   srcs   = (int*)(binned + e);

        int chunk = (((e + NBLK3 - 1) / NBLK3) + 3) & ~3;  // multiple of 4 for int4 path

        bhist_kernel<<<NBLK3, BT3, 0, stream>>>(col, hist, e, chunk);
        colscan_kernel<<<MAXNB, 256, 0, stream>>>(hist, total);
        basescan_kernel<<<1, MAXNB, 0, stream>>>(total, base, nb, e);
        bscatter_kernel<<<NBLK3, BT3, 0, stream>>>(row, col, hist, base, binned, e, chunk);
        bucket_build_kernel<<<nb, 512, 0, stream>>>(base, binned, offend, dis, srcs, n);
        xw_t_gemm_kernel<<<(n + BM - 1) / BM, 256, 0, stream>>>(x, W, dis, t, n);
        gather8_kernel<<<(n + 3) / 4, 256, 0, stream>>>(offend, srcs, t, dis, b, out, n);
    } else if (ws_size >= mid_needed) {
        int*   cnt    = (int*)d_ws;
        int*   offend = cnt + nA;
        int*   bsum   = offend + 2 * nA;
        float* dis    = (float*)(bsum + 1024);
        unsigned short* t = (unsigned short*)(dis + nA);
        int*   srcs   = (int*)(t + nA * D);

        int nblk = (n + 1023) / 1024;
        cnt_init_kernel<<<(n + 255) / 256, 256, 0, stream>>>(cnt, n);
        hist_kernel<<<(e + 255) / 256, 256, 0, stream>>>(col, cnt, e);
        scan1_kernel<<<nblk, 1024, 0, stream>>>(cnt, dis, offend, bsum, n);
        scan2_kernel<<<1, 1024, 0, stream>>>(bsum, nblk);
        scan3_kernel<<<nblk, 1024, 0, stream>>>(offend, bsum, n);
        xw_t_gemm_kernel<<<(n + BM - 1) / BM, 256, 0, stream>>>(x, W, dis, t, n);
        fill_kernel<<<(e + 255) / 256, 256, 0, stream>>>(row, col, offend, srcs, e);
        gather8_kernel<<<(n + 3) / 4, 256, 0, stream>>>(offend, srcs, t, dis, b, out, n);
    } else {
        float* deg = (float*)d_ws;
        float* xw  = deg + nA;
        deg_init_kernel<<<(n + 255) / 256, 256, 0, stream>>>(deg, n);
        deg_count_kernel<<<(e + 255) / 256, 256, 0, stream>>>(col, deg, e);
        deg_rsqrt_kernel<<<(n + 255) / 256, 256, 0, stream>>>(deg, n);
        xw_kernel<<<(n + 3) / 4, 256, 0, stream>>>(x, W, xw, n);
        out_init_kernel<<<((size_t)n * D + 255) / 256, 256, 0, stream>>>(xw, deg, b, out, n);
        scatter_kernel<<<(e + 3) / 4, 256, 0, stream>>>(row, col, deg, xw, out, e);
    }
}

// Round 16
// 103.001 us; speedup vs baseline: 1.0260x; 1.0260x over previous
//
#include <hip/hip_runtime.h>

// GCNConv forward via radix-partitioned CSR build + bf16 register gather.
// t[i] = bf16( dis[i]*(x@W)[i] );  out[c] = b + dis[c]*( t[c] + sum_{edges r->c} t[r] )
//
// NOTE: workspace layout keeps t 256-B aligned — a 32-B-aligned t makes every
// gathered 128-B row straddle two cache lines (R10: FETCH +78%, +9 us).
// CSR build uses deterministic per-(block,bucket) offsets (radix-sort partition):
// no global reservation atomics (R9 lesson: per-address chains serialize NBLK-deep).
// R15 lesson: dropping the odd-element AND masks in add8 raises VGPR 32->36 and
// drops occupancy 69->60% (longer uint4 lifetimes) — a net LOSS; keep the masks.

#define D 64
#define BSH 8            // bucket shift: 256 cols per bucket
#define BCOLS 256
#define MAXNB 512        // supports n <= 131072 (row fits in 20 bits)
#define BM 128           // GEMM rows per block
#define NBLK3 512        // partition blocks
#define BT3 512          // partition threads per block
#define BB_CACHE 6144    // bucket_build LDS edge cache (24 KB)

__device__ inline unsigned short f2bf(float f) {   // RNE fp32 -> bf16
    unsigned u = __float_as_uint(f);
    return (unsigned short)((u + 0x7FFFu + ((u >> 16) & 1u)) >> 16);
}

// ---------- fast path: radix-partitioned CSR build ----------

// Pass 1: per-block bucket histogram of its chunk -> hist[block][MAXNB].
__global__ __launch_bounds__(BT3) void bhist_kernel(const int* __restrict__ col, int* __restrict__ hist,
                                                    int e, int chunk) {
    __shared__ int h[MAXNB];
    int tid = threadIdx.x;
    for (int i = tid; i < MAXNB; i += BT3) h[i] = 0;
    __syncthreads();
    int i0 = blockIdx.x * chunk;
    int i1 = i0 + chunk; if (i1 > e) i1 = e;
    if (((e | chunk) & 3) == 0) {
        for (int i = i0 + tid * 4; i < i1; i += BT3 * 4) {
            int4 c4 = *(const int4*)(col + i);
            atomicAdd(&h[c4.x >> BSH], 1);
            atomicAdd(&h[c4.y >> BSH], 1);
            atomicAdd(&h[c4.z >> BSH], 1);
            atomicAdd(&h[c4.w >> BSH], 1);
        }
    } else {
        for (int i = i0 + tid; i < i1; i += BT3)
            atomicAdd(&h[col[i] >> BSH], 1);
    }
    __syncthreads();
    for (int i = tid; i < MAXNB; i += BT3)
        hist[blockIdx.x * MAXNB + i] = h[i];
}

// Pass 2: one block per bucket: exclusive scan of hist[:, b] across NBLK3 rows (in place),
// bucket total -> total[b].
__global__ __launch_bounds__(256) void colscan_kernel(int* __restrict__ hist, int* __restrict__ total) {
    __shared__ int s[256];
    int b = blockIdx.x;
    int tid = threadIdx.x;
    int v0 = hist[(2 * tid) * MAXNB + b];
    int v1 = hist[(2 * tid + 1) * MAXNB + b];
    int sum = v0 + v1;
    s[tid] = sum;
    __syncthreads();
#pragma unroll
    for (int d = 1; d < 256; d <<= 1) {
        int add = (tid >= d) ? s[tid - d] : 0;
        __syncthreads();
        s[tid] += add;
        __syncthreads();
    }
    int ex = s[tid] - sum;
    hist[(2 * tid) * MAXNB + b] = ex;
    hist[(2 * tid + 1) * MAXNB + b] = ex + v0;
    if (tid == 255) total[b] = s[255];
}

// Pass 3: exclusive scan of total[0..MAXNB) -> base (base[nb] = e via zero padding).
__global__ __launch_bounds__(MAXNB) void basescan_kernel(const int* __restrict__ total, int* __restrict__ base,
                                                         int nb, int e) {
    __shared__ int s[MAXNB];
    int tid = threadIdx.x;
    int v = total[tid];
    s[tid] = v;
    __syncthreads();
#pragma unroll
    for (int d = 1; d < MAXNB; d <<= 1) {
        int add = (tid >= d) ? s[tid - d] : 0;
        __syncthreads();
        s[tid] += add;
        __syncthreads();
    }
    base[tid] = s[tid] - v;
    if (tid == 0) base[nb] = e;
}

// Pass 4: scatter edges bucket-grouped. Deterministic start = base[b] + hist[block][b];
// LDS-only cursors, no global atomics. binned[pos] = ((col&255) << 20) | row.
__global__ __launch_bounds__(BT3) void bscatter_kernel(const int* __restrict__ row, const int* __restrict__ col,
                                                       const int* __restrict__ hist, const int* __restrict__ base,
                                                       unsigned int* __restrict__ binned, int e, int chunk) {
    __shared__ int h[MAXNB];
    int tid = threadIdx.x;
    for (int i = tid; i < MAXNB; i += BT3)
        h[i] = base[i] + hist[blockIdx.x * MAXNB + i];
    __syncthreads();
    int i0 = blockIdx.x * chunk;
    int i1 = i0 + chunk; if (i1 > e) i1 = e;
    if (((e | chunk) & 3) == 0) {
        for (int i = i0 + tid * 4; i < i1; i += BT3 * 4) {
            int4 c4 = *(const int4*)(col + i);
            int4 r4 = *(const int4*)(row + i);
            int bk, pos;
            bk = c4.x >> BSH; pos = atomicAdd(&h[bk], 1);
            binned[pos] = ((unsigned int)(c4.x & (BCOLS - 1)) << 20) | (unsigned int)r4.x;
            bk = c4.y >> BSH; pos = atomicAdd(&h[bk], 1);
            binned[pos] = ((unsigned int)(c4.y & (BCOLS - 1)) << 20) | (unsigned int)r4.y;
            bk = c4.z >> BSH; pos = atomicAdd(&h[bk], 1);
            binned[pos] = ((unsigned int)(c4.z & (BCOLS - 1)) << 20) | (unsigned int)r4.z;
            bk = c4.w >> BSH; pos = atomicAdd(&h[bk], 1);
            binned[pos] = ((unsigned int)(c4.w & (BCOLS - 1)) << 20) | (unsigned int)r4.w;
        }
    } else {
        for (int i = i0 + tid; i < i1; i += BT3) {
            int cl = col[i];
            int bk = cl >> BSH;
            int pos = atomicAdd(&h[bk], 1);
            binned[pos] = ((unsigned int)(cl & (BCOLS - 1)) << 20) | (unsigned int)row[i];
        }
    }
}

// One block (512 threads) per 256-col bucket: per-col hist -> 256-wide scan ->
// offend (int2 per col) + dis + srcs. Binned chunk cached in LDS when it fits.
__global__ __launch_bounds__(512) void bucket_build_kernel(const int* __restrict__ base,
                                                           const unsigned int* __restrict__ binned,
                                                           int* __restrict__ offend,
                                                           float* __restrict__ dis, int* __restrict__ srcs,
                                                           int n) {
    __shared__ int hc[BCOLS];
    __shared__ int ho[BCOLS];
    __shared__ int hcur[BCOLS];
    __shared__ unsigned int bc[BB_CACHE];
    int tid = threadIdx.x;
    int b = blockIdx.x;
    int s0 = base[b], s1 = base[b + 1];
    int m = s1 - s0;
    bool cached = (m <= BB_CACHE);
    if (cached)
        for (int i = tid; i < m; i += 512) bc[i] = binned[s0 + i];
    if (tid < BCOLS) hc[tid] = 0;
    __syncthreads();
    if (cached) {
        for (int i = tid; i < m; i += 512)
            atomicAdd(&hc[(bc[i] >> 20) & (BCOLS - 1)], 1);
    } else {
        for (int i = s0 + tid; i < s1; i += 512)
            atomicAdd(&hc[(binned[i] >> 20) & (BCOLS - 1)], 1);
    }
    __syncthreads();
    int v = 0;
    if (tid < BCOLS) { v = hc[tid]; ho[tid] = v; }
    __syncthreads();
#pragma unroll
    for (int d = 1; d < BCOLS; d <<= 1) {
        int add = (tid < BCOLS && tid >= d) ? ho[tid - d] : 0;
        __syncthreads();
        if (tid < BCOLS) ho[tid] += add;
        __syncthreads();
    }
    if (tid < BCOLS) {
        int col = (b << BSH) + tid;
        if (col < n) {
            int ex = ho[tid] - v;
            ((int2*)offend)[col] = make_int2(s0 + ex, s0 + ho[tid]);
            dis[col] = rsqrtf((float)(v + 1));  // +1 self loop
            hcur[tid] = s0 + ex;
        }
    }
    __syncthreads();
    if (cached) {
        for (int i = tid; i < m; i += 512) {
            unsigned int w = bc[i];
            int lc = (w >> 20) & (BCOLS - 1);
            int pos = atomicAdd(&hcur[lc], 1);
            srcs[pos] = (int)(w & 0xFFFFFu);
        }
    } else {
        for (int i = s0 + tid; i < s1; i += 512) {
            unsigned int w = binned[i];
            int lc = (w >> 20) & (BCOLS - 1);
            int pos = atomicAdd(&hcur[lc], 1);
            srcs[pos] = (int)(w & 0xFFFFFu);
        }
    }
}

// ---------- t = bf16( dis * (x @ W) ): register-tiled fp32 GEMM ----------

__global__ __launch_bounds__(256) void xw_t_gemm_kernel(const float* __restrict__ x, const float* __restrict__ W,
                                                        const float* __restrict__ dis,
                                                        unsigned short* __restrict__ t, int n) {
    __shared__ float xT[D][BM];   // [k][row], 32 KB
    __shared__ float Wl[D][D];    // [k][col], 16 KB
    int tid = threadIdx.x;
    int r0 = blockIdx.x * BM;

    {
        const float4* Wv = (const float4*)W;
        float4* Wd = (float4*)&Wl[0][0];
#pragma unroll
        for (int j = 0; j < 4; ++j) Wd[j * 256 + tid] = Wv[j * 256 + tid];
    }
    {
        int row = tid >> 1;
        int c0 = (tid & 1) * 32;
        int gr = r0 + row;
        if (gr < n) {
            const float4* xv = (const float4*)(x + (size_t)gr * D + c0);
#pragma unroll
            for (int j = 0; j < 8; ++j) {
                float4 v = xv[j];
                int c = c0 + j * 4;
                xT[c + 0][row] = v.x;
                xT[c + 1][row] = v.y;
                xT[c + 2][row] = v.z;
                xT[c + 3][row] = v.w;
            }
        }
    }
    __syncthreads();

    int cg = tid & 15;
    int rg = tid >> 4;
    float acc[8][4];
#pragma unroll
    for (int i = 0; i < 8; ++i)
#pragma unroll
        for (int j = 0; j < 4; ++j) acc[i][j] = 0.0f;

#pragma unroll 8
    for (int k = 0; k < D; ++k) {
        float4 xa = *(const float4*)&xT[k][rg * 8];
        float4 xb = *(const float4*)&xT[k][rg * 8 + 4];
        float4 wv = *(const float4*)&Wl[k][cg * 4];
        float xr[8] = {xa.x, xa.y, xa.z, xa.w, xb.x, xb.y, xb.z, xb.w};
        float wr[4] = {wv.x, wv.y, wv.z, wv.w};
#pragma unroll
        for (int i = 0; i < 8; ++i)
#pragma unroll
            for (int j = 0; j < 4; ++j) acc[i][j] += xr[i] * wr[j];
    }

#pragma unroll
    for (int i = 0; i < 8; ++i) {
        int gr = r0 + rg * 8 + i;
        if (gr < n) {
            float dsc = dis[gr];
            ushort4 o;
            o.x = f2bf(acc[i][0] * dsc); o.y = f2bf(acc[i][1] * dsc);
            o.z = f2bf(acc[i][2] * dsc); o.w = f2bf(acc[i][3] * dsc);
            *(ushort4*)(t + (size_t)gr * D + cg * 4) = o;
        }
    }
}

// ---------- gather: one wave per node, 8-edge subgroups, bf16 rows ----------

__device__ inline void add8(float* acc, uint4 u) {
    acc[0] += __uint_as_float(u.x << 16);
    acc[1] += __uint_as_float(u.x & 0xFFFF0000u);
    acc[2] += __uint_as_float(u.y << 16);
    acc[3] += __uint_as_float(u.y & 0xFFFF0000u);
    acc[4] += __uint_as_float(u.z << 16);
    acc[5] += __uint_as_float(u.z & 0xFFFF0000u);
    acc[6] += __uint_as_float(u.w << 16);
    acc[7] += __uint_as_float(u.w & 0xFFFF0000u);
}

__global__ __launch_bounds__(256) void gather8_kernel(const int* __restrict__ offend,
                                                      const int* __restrict__ srcs,
                                                      const unsigned short* __restrict__ t,
                                                      const float* __restrict__ dis, const float* __restrict__ b,
                                                      float* __restrict__ out, int n) {
    int c    = blockIdx.x * 4 + (threadIdx.x >> 6);
    int lane = threadIdx.x & 63;
    if (c >= n) return;
    int e8 = lane >> 3;   // edge subgroup 0..7
    int d8 = lane & 7;    // 16B chunk of row
    int2 oe = ((const int2*)offend)[c];
    int j0 = oe.x;
    int jend = oe.y;

    float acc[8];
#pragma unroll
    for (int q = 0; q < 8; ++q) acc[q] = 0.0f;

    if (e8 == 0) {  // self-loop term
        uint4 u = *(const uint4*)(t + (size_t)c * D + d8 * 8);
        add8(acc, u);
    }

    for (int jb = j0; jb < jend; jb += 64) {
        int m = jend - jb; if (m > 64) m = 64;
        int sv = (jb + lane < jend) ? srcs[jb + lane] : 0;
        int k = 0;
        for (; k + 32 <= m; k += 32) {   // 4 independent loads in flight
            int r0 = __shfl(sv, k + e8);
            int r1 = __shfl(sv, k + 8 + e8);
            int r2 = __shfl(sv, k + 16 + e8);
            int r3 = __shfl(sv, k + 24 + e8);
            uint4 u0 = *(const uint4*)(t + (size_t)r0 * D + d8 * 8);
            uint4 u1 = *(const uint4*)(t + (size_t)r1 * D + d8 * 8);
            uint4 u2 = *(const uint4*)(t + (size_t)r2 * D + d8 * 8);
            uint4 u3 = *(const uint4*)(t + (size_t)r3 * D + d8 * 8);
            add8(acc, u0); add8(acc, u1); add8(acc, u2); add8(acc, u3);
        }
        for (; k + 16 <= m; k += 16) {
            int r0 = __shfl(sv, k + e8);
            int r1 = __shfl(sv, k + 8 + e8);
            uint4 u0 = *(const uint4*)(t + (size_t)r0 * D + d8 * 8);
            uint4 u1 = *(const uint4*)(t + (size_t)r1 * D + d8 * 8);
            add8(acc, u0); add8(acc, u1);
        }
        for (; k < m; k += 8) {
            int idx = k + e8;
            int r = __shfl(sv, idx);
            if (idx < m) {
                uint4 u = *(const uint4*)(t + (size_t)r * D + d8 * 8);
                add8(acc, u);
            }
        }
    }

#pragma unroll
    for (int s = 8; s < 64; s <<= 1)
#pragma unroll
        for (int q = 0; q < 8; ++q) acc[q] += __shfl_xor(acc[q], s);

    if (e8 == 0) {
        float dsc = dis[c];
        float* op = out + (size_t)c * D + d8 * 8;
        const float* bp = b + d8 * 8;
        float4 o0, o1;
        o0.x = bp[0] + dsc * acc[0]; o0.y = bp[1] + dsc * acc[1];
        o0.z = bp[2] + dsc * acc[2]; o0.w = bp[3] + dsc * acc[3];
        o1.x = bp[4] + dsc * acc[4]; o1.y = bp[5] + dsc * acc[5];
        o1.z = bp[6] + dsc * acc[6]; o1.w = bp[7] + dsc * acc[7];
        *(float4*)op = o0;
        *(float4*)(op + 4) = o1;
    }
}

// ---------- mid fallback: flat hist/scan/fill CSR + gather8 (offend layout) ----------

__global__ __launch_bounds__(256) void cnt_init_kernel(int* __restrict__ cnt, int n) {
    int i = blockIdx.x * 256 + threadIdx.x;
    if (i < n) cnt[i] = 0;
}
__global__ __launch_bounds__(256) void hist_kernel(const int* __restrict__ col, int* __restrict__ cnt, int e) {
    int i = blockIdx.x * 256 + threadIdx.x;
    if (i < e) atomicAdd(&cnt[col[i]], 1);
}
__global__ __launch_bounds__(1024) void scan1_kernel(const int* __restrict__ cnt, float* __restrict__ dis,
                                                     int* __restrict__ offend, int* __restrict__ bsum, int n) {
    __shared__ int s[1024];
    int tid = threadIdx.x;
    int i = blockIdx.x * 1024 + tid;
    int v = (i < n) ? cnt[i] : 0;
    if (i < n) dis[i] = rsqrtf((float)(v + 1));
    s[tid] = v;
    __syncthreads();
#pragma unroll
    for (int d = 1; d < 1024; d <<= 1) {
        int add = (tid >= d) ? s[tid - d] : 0;
        __syncthreads();
        s[tid] += add;
        __syncthreads();
    }
    int incl = s[tid];
    if (i < n) offend[2 * i] = incl - v;
    if (tid == 1023) bsum[blockIdx.x] = incl;
}
__global__ __launch_bounds__(1024) void scan2_kernel(int* __restrict__ bsum, int nb) {
    __shared__ int s[1024];
    int tid = threadIdx.x;
    int v = (tid < nb) ? bsum[tid] : 0;
    s[tid] = v;
    __syncthreads();
#pragma unroll
    for (int d = 1; d < 1024; d <<= 1) {
        int add = (tid >= d) ? s[tid - d] : 0;
        __syncthreads();
        s[tid] += add;
        __syncthreads();
    }
    if (tid < nb) bsum[tid] = s[tid] - v;
}
__global__ __launch_bounds__(1024) void scan3_kernel(int* __restrict__ offend, const int* __restrict__ bsum, int n) {
    int i = blockIdx.x * 1024 + threadIdx.x;
    if (i < n) {
        int o = offend[2 * i] + bsum[blockIdx.x];
        offend[2 * i] = o;
        offend[2 * i + 1] = o;
    }
}
__global__ __launch_bounds__(256) void fill_kernel(const int* __restrict__ row, const int* __restrict__ col,
                                                   int* __restrict__ offend, int* __restrict__ srcs, int e) {
    int i = blockIdx.x * 256 + threadIdx.x;
    if (i < e) {
        int pos = atomicAdd(&offend[2 * col[i] + 1], 1);
        srcs[pos] = row[i];
    }
}

// ---------- last fallback: atomic scatter ----------

__global__ __launch_bounds__(256) void deg_init_kernel(float* __restrict__ deg, int n) {
    int i = blockIdx.x * 256 + threadIdx.x;
    if (i < n) deg[i] = 1.0f;
}
__global__ __launch_bounds__(256) void deg_count_kernel(const int* __restrict__ col, float* __restrict__ deg, int e) {
    int i = blockIdx.x * 256 + threadIdx.x;
    if (i < e) atomicAdd(&deg[col[i]], 1.0f);
}
__global__ __launch_bounds__(256) void deg_rsqrt_kernel(float* __restrict__ deg, int n) {
    int i = blockIdx.x * 256 + threadIdx.x;
    if (i < n) deg[i] = rsqrtf(deg[i]);
}
__global__ __launch_bounds__(256) void xw_kernel(const float* __restrict__ x, const float* __restrict__ W,
                                                 float* __restrict__ xw, int n) {
    __shared__ float Wl[D * D];
    int tid = threadIdx.x;
    for (int i = tid; i < D * D; i += 256) Wl[i] = W[i];
    __syncthreads();
    int lane = tid & 63;
    int row  = blockIdx.x * 4 + (tid >> 6);
    if (row >= n) return;
    float xv = x[(size_t)row * D + lane];
    float acc = 0.0f;
#pragma unroll
    for (int k = 0; k < D; ++k) acc += __shfl(xv, k) * Wl[k * D + lane];
    xw[(size_t)row * D + lane] = acc;
}
__global__ __launch_bounds__(256) void out_init_kernel(const float* __restrict__ xw, const float* __restrict__ dis,
                                                       const float* __restrict__ b, float* __restrict__ out, int n) {
    int i = blockIdx.x * 256 + threadIdx.x;
    if (i < n * D) {
        int node = i >> 6;
        float d = dis[node];
        out[i] = b[i & 63] + d * d * xw[i];
    }
}
__global__ __launch_bounds__(256) void scatter_kernel(const int* __restrict__ row, const int* __restrict__ col,
                                                      const float* __restrict__ dis, const float* __restrict__ xw,
                                                      float* __restrict__ out, int e) {
    int idx  = blockIdx.x * 4 + (threadIdx.x >> 6);
    int lane = threadIdx.x & 63;
    if (idx >= e) return;
    int r = row[idx], c = col[idx];
    float w = dis[r] * dis[c];
    atomicAdd(&out[(size_t)c * D + lane], w * xw[(size_t)r * D + lane]);
}

// ---------- launch ----------

extern "C" void kernel_launch(void* const* d_in, const int* in_sizes, int n_in,
                              void* d_out, int out_size, void* d_ws, size_t ws_size,
                              hipStream_t stream) {
    const float* x  = (const float*)d_in[0];
    const int*   ei = (const int*)d_in[1];
    const float* W  = (const float*)d_in[2];
    const float* b  = (const float*)d_in[3];
    float*       out = (float*)d_out;

    int n = in_sizes[0] / D;   // 100000
    int e = in_sizes[1] / 2;   // 1600000
    const int* row = ei;
    const int* col = ei + e;

    size_t nA = ((size_t)n + 255) & ~(size_t)255;  // multiple of 256 elems -> 1 KB
    int nb = (n + BCOLS - 1) >> BSH;

    // fast: hist[NBLK3*MAXNB] | total[512] base[520] pad (2048 ints) | offend[2*nA] | dis[nA] |
    //       t[nA*D] bf16 | binned[e] srcs[e].  All section sizes 256-B multiples -> t 256-B aligned.
    size_t histN = (size_t)NBLK3 * MAXNB;
    size_t fast_needed = (histN + 2048) * 4 + 2 * nA * 4 + nA * 4 + nA * D * 2 + 2 * (size_t)e * 4;
    size_t mid_needed  = (2 * nA + nA + 1024) * 4 + nA * 4 + nA * D * 2 + (size_t)e * 4;

    if (n <= 131072 && nb <= MAXNB && ws_size >= fast_needed) {
        int*   hist   = (int*)d_ws;
        int*   total  = hist + histN;
        int*   base   = total + 512;
        int*   offend = hist + histN + 2048;
        float* dis    = (float*)(offend + 2 * nA);
        unsigned short* t = (unsigned short*)(dis + nA);
        unsigned int* binned = (unsigned int*)(t + nA * D);
        int*   srcs   = (int*)(binned + e);

        int chunk = (((e + NBLK3 - 1) / NBLK3) + 3) & ~3;  // multiple of 4 for int4 path

        bhist_kernel<<<NBLK3, BT3, 0, stream>>>(col, hist, e, chunk);
        colscan_kernel<<<MAXNB, 256, 0, stream>>>(hist, total);
        basescan_kernel<<<1, MAXNB, 0, stream>>>(total, base, nb, e);
        bscatter_kernel<<<NBLK3, BT3, 0, stream>>>(row, col, hist, base, binned, e, chunk);
        bucket_build_kernel<<<nb, 512, 0, stream>>>(base, binned, offend, dis, srcs, n);
        xw_t_gemm_kernel<<<(n + BM - 1) / BM, 256, 0, stream>>>(x, W, dis, t, n);
        gather8_kernel<<<(n + 3) / 4, 256, 0, stream>>>(offend, srcs, t, dis, b, out, n);
    } else if (ws_size >= mid_needed) {
        int*   cnt    = (int*)d_ws;
        int*   offend = cnt + nA;
        int*   bsum   = offend + 2 * nA;
        float* dis    = (float*)(bsum + 1024);
        unsigned short* t = (unsigned short*)(dis + nA);
        int*   srcs   = (int*)(t + nA * D);

        int nblk = (n + 1023) / 1024;
        cnt_init_kernel<<<(n + 255) / 256, 256, 0, stream>>>(cnt, n);
        hist_kernel<<<(e + 255) / 256, 256, 0, stream>>>(col, cnt, e);
        scan1_kernel<<<nblk, 1024, 0, stream>>>(cnt, dis, offend, bsum, n);
        scan2_kernel<<<1, 1024, 0, stream>>>(bsum, nblk);
        scan3_kernel<<<nblk, 1024, 0, stream>>>(offend, bsum, n);
        xw_t_gemm_kernel<<<(n + BM - 1) / BM, 256, 0, stream>>>(x, W, dis, t, n);
        fill_kernel<<<(e + 255) / 256, 256, 0, stream>>>(row, col, offend, srcs, e);
        gather8_kernel<<<(n + 3) / 4, 256, 0, stream>>>(offend, srcs, t, dis, b, out, n);
    } else {
        float* deg = (float*)d_ws;
        float* xw  = deg + nA;
        deg_init_kernel<<<(n + 255) / 256, 256, 0, stream>>>(deg, n);
        deg_count_kernel<<<(e + 255) / 256, 256, 0, stream>>>(col, deg, e);
        deg_rsqrt_kernel<<<(n + 255) / 256, 256, 0, stream>>>(deg, n);
        xw_kernel<<<(n + 3) / 4, 256, 0, stream>>>(x, W, xw, n);
        out_init_kernel<<<((size_t)n * D + 255) / 256, 256, 0, stream>>>(xw, deg, b, out, n);
        scatter_kernel<<<(e + 3) / 4, 256, 0, stream>>>(row, col, deg, xw, out, e);
    }
}